// Round 2
// baseline (283.724 us; speedup 1.0000x reference)
//
#include <hip/hip_runtime.h>

typedef __attribute__((ext_vector_type(8)))  short short8;   // 8 bf16 (4 VGPRs)
typedef __attribute__((ext_vector_type(16))) float f32x16;   // 32x32 MFMA acc
typedef unsigned short ushort_t;
typedef unsigned int uint32;

#define NROWS 8192
#define NCODE 8192
#define DIM   512

// ---------------- d_out layout (floats) ----------------
#define OUT_Q      0
#define OUT_LOSS   4194304
#define OUT_IDX    4194305
#define OUT_MIND   4202497
#define OUT_COMMIT 4210689

// ---------------- ws layout (floats) ----------------
#define WS_ENORM  0           // 8192
#define WS_PMIN   8192        // 8192*8
#define WS_PIDX   73728       // 8192*8 ints
#define WS_LPART  147456      // 2048
#define WS_BHI    150528      // 8192*512 bf16
#define WS_BLO    2247680

// ===========================================================================
__device__ inline uint32 bf16_rne(float f) {
    uint32 u = __float_as_uint(f);
    return (u + 0x7FFFu + ((u >> 16) & 1u)) >> 16;
}

__device__ inline void gload16(const ushort_t* g, ushort_t* l) {
    __builtin_amdgcn_global_load_lds(
        (const __attribute__((address_space(1))) void*)g,
        (__attribute__((address_space(3))) void*)l, 16, 0, 0);
}

// ===========================================================================
// Kernel 1: fused conversion of x and codebook into fragment-ordered bf16
// hi/lo tiles. Tile = 128 rows x 32 k, 8 KB, stored as 8 chunks of 1 KB:
//   chunk c = (r32)*2 + k16 ; within chunk lane L holds 8 bf16:
//   row = r32*32 + (L&31), k = k16*16 + (L>>5)*8 + j
// This IS the mfma_32x32x16 A/B fragment order -> conflict-free ds_read_b128
// and identity global_load_lds staging.
__global__ __launch_bounds__(256) void conv_kernel(const float* __restrict__ x,
                                                   const float* __restrict__ cb,
                                                   ushort_t* __restrict__ ahi,
                                                   ushort_t* __restrict__ alo,
                                                   ushort_t* __restrict__ bhi,
                                                   ushort_t* __restrict__ blo,
                                                   float* __restrict__ enorm) {
    int gid  = blockIdx.x * 256 + threadIdx.x;   // 0..1048575
    bool isA = gid < 524288;
    int g    = isA ? gid : gid - 524288;
    int row  = g >> 6;
    int lane = g & 63;
    int k0   = lane * 8;
    const float* src = (isA ? x : cb) + (size_t)row * DIM + k0;
    float v[8];
    *(float4*)&v[0] = *(const float4*)src;
    *(float4*)&v[4] = *(const float4*)(src + 4);
    float s = 0.0f;
    uint32 h[8], l[8];
    #pragma unroll
    for (int i = 0; i < 8; ++i) {
        s += v[i] * v[i];
        h[i] = bf16_rne(v[i]);
        float hf = __uint_as_float(h[i] << 16);
        l[i] = bf16_rne(v[i] - hf);
    }
    // fragment-ordered offset
    int tile = (row >> 7) * 16 + (k0 >> 5);
    int rp = row & 127, kp = k0 & 31;
    int c  = (rp >> 5) * 2 + (kp >> 4);
    int L  = (rp & 31) + (((kp >> 3) & 1) << 5);
    size_t off = (size_t)tile * 4096 + c * 512 + L * 8;   // ushort units
    uint4 ph, pl;
    ph.x = h[0] | (h[1] << 16); ph.y = h[2] | (h[3] << 16);
    ph.z = h[4] | (h[5] << 16); ph.w = h[6] | (h[7] << 16);
    pl.x = l[0] | (l[1] << 16); pl.y = l[2] | (l[3] << 16);
    pl.z = l[4] | (l[5] << 16); pl.w = l[6] | (l[7] << 16);
    if (isA) {
        *(uint4*)(ahi + off) = ph;
        *(uint4*)(alo + off) = pl;
    } else {
        *(uint4*)(bhi + off) = ph;
        *(uint4*)(blo + off) = pl;
        #pragma unroll
        for (int o = 32; o > 0; o >>= 1) s += __shfl_down(s, o);
        if (lane == 0) enorm[row] = s;
    }
}

// ===========================================================================
// Kernel 2: MFMA distance-GEMM + fused per-row argmin.
// R2 restructure: LDS-bytes-per-MFMA was the wall (1.0 KB/MFMA; MfmaUtil
// schedule-invariant at 51%). Now: 512-thread block, 8 waves (4 row x 2 col
// groups), wave tile 64x128 (acc[2][4]), block K-step tile 256 rows x 256
// cols. LDS per MFMA: 0.5 KB read + 0.167 KB staged = 0.67 (was 1.0).
// LDS = 2 x 64 KB double buffer (128 KB), 1 block/CU, 2 waves/SIMD.
// Argmin reduction is now pure-shuffle (each row owned by one wave).
// Grid 256: bx = (q&7)*4 + (q>>6) (XCD-chunked, A slice 2 MB/XCD L2-res),
// by = (q>>3)&7 -> 1024-col slice, inner loop ct(4) x kb(16) = 64 iters.
__global__ __launch_bounds__(512, 2) void vq_mfma_kernel(
        const ushort_t* __restrict__ ahi, const ushort_t* __restrict__ alo,
        const ushort_t* __restrict__ bhi, const ushort_t* __restrict__ blo,
        const float* __restrict__ enorm,
        float* __restrict__ pmin, int* __restrict__ pidx) {
    // 2 x 32768 ushorts: per buffer AH[0,16K) AL[16K,32K) BH[32K,48K) BL[48K,64K) bytes
    __shared__ __align__(16) ushort_t smem[65536];   // 128 KB

    const int tid  = threadIdx.x;            // 0..511
    const int wave = tid >> 6, lane = tid & 63;
    const int l31  = lane & 31, half = lane >> 5;
    const int q  = blockIdx.x;
    const int bx = (q & 7) * 4 + (q >> 6);   // 0..31 (256-row block)
    const int by = (q >> 3) & 7;             // 0..7  (1024-col slice)
    const int wr = wave >> 1;                // 0..3 row group (64 rows)
    const int wc = wave & 1;                 // 0..1 col group (128 cols)
    const int wrow = wr * 64, wcol = wc * 128;
    const int so = tid * 8;                  // ushort offset, 8 KB per sweep

    f32x16 acc[2][4];
    #pragma unroll
    for (int i = 0; i < 2; ++i)
        #pragma unroll
        for (int j = 0; j < 4; ++j)
            #pragma unroll
            for (int r = 0; r < 16; ++r) acc[i][j][r] = 0.0f;

    float  bestd[32];
    uint32 bi2[16];                          // 2 packed 16-bit indices per reg
    #pragma unroll
    for (int i = 0; i < 32; ++i) bestd[i] = 3.4e38f;
    #pragma unroll
    for (int i = 0; i < 16; ++i) bi2[i] = 0u;

    // ---- staging halves for tile nn into buffer nn&1 (4 gloads each) ----
    auto stageA = [&](int nn) {
        const int kb = nn & 15;
        ushort_t* S2 = smem + (nn & 1) * 32768;
        const size_t a0 = (size_t)((2 * bx)     * 16 + kb) * 4096;
        const size_t a1 = (size_t)((2 * bx + 1) * 16 + kb) * 4096;
        gload16(ahi + a0 + so, S2 + so);
        gload16(ahi + a1 + so, S2 + 4096 + so);
        gload16(alo + a0 + so, S2 + 8192 + so);
        gload16(alo + a1 + so, S2 + 12288 + so);
    };
    auto stageB = [&](int nn) {
        const int kb = nn & 15;
        const int c0 = by * 8 + (nn >> 4) * 2;     // first of 2 col-tiles
        ushort_t* S2 = smem + (nn & 1) * 32768;
        const size_t b0 = (size_t)(c0       * 16 + kb) * 4096;
        const size_t b1 = (size_t)((c0 + 1) * 16 + kb) * 4096;
        gload16(bhi + b0 + so, S2 + 16384 + so);
        gload16(bhi + b1 + so, S2 + 20480 + so);
        gload16(blo + b0 + so, S2 + 24576 + so);
        gload16(blo + b1 + so, S2 + 28672 + so);
    };

    stageA(0); stageB(0);

    #pragma unroll 2
    for (int n = 0; n < 64; ++n) {
        ushort_t* S = smem + (n & 1) * 32768;

        // issue next A-half; counted publish wait (A(n),B(n) landed,
        // A(n+1) stays in flight across the barrier)
        if (n < 63) {
            stageA(n + 1);
            asm volatile("s_waitcnt vmcnt(4)" ::: "memory");
        } else {
            asm volatile("s_waitcnt vmcnt(0)" ::: "memory");
        }
        asm volatile("s_barrier" ::: "memory");      // publish tile n
        __builtin_amdgcn_sched_barrier(0);

        // ---- both k16 phases, no intermediate barrier (read-only buffer;
        //      compiler free to overlap phase-1 reads with phase-0 MFMAs) ----
        #pragma unroll
        for (int p = 0; p < 2; ++p) {
            short8 ah[2], al[2], bh[4], bl[4];
            #pragma unroll
            for (int ti = 0; ti < 2; ++ti) {
                int c = (wr * 2 + ti) * 2 + p;
                ah[ti] = *(const short8*)&S[c * 512 + lane * 8];
                al[ti] = *(const short8*)&S[8192 + c * 512 + lane * 8];
            }
            #pragma unroll
            for (int tj = 0; tj < 4; ++tj) {
                int c = (wc * 4 + tj) * 2 + p;
                bh[tj] = *(const short8*)&S[16384 + c * 512 + lane * 8];
                bl[tj] = *(const short8*)&S[24576 + c * 512 + lane * 8];
            }
            if (p == 0 && n < 63) stageB(n + 1);   // flies under MFMAs
            __builtin_amdgcn_s_setprio(1);
            // three sweeps of 8 independent MFMAs (dep distance 8)
            #pragma unroll
            for (int ti = 0; ti < 2; ++ti)
                #pragma unroll
                for (int tj = 0; tj < 4; ++tj)
                    acc[ti][tj] = __builtin_amdgcn_mfma_f32_32x32x16_bf16(
                        ah[ti], bh[tj], acc[ti][tj], 0, 0, 0);
            #pragma unroll
            for (int ti = 0; ti < 2; ++ti)
                #pragma unroll
                for (int tj = 0; tj < 4; ++tj)
                    acc[ti][tj] = __builtin_amdgcn_mfma_f32_32x32x16_bf16(
                        ah[ti], bl[tj], acc[ti][tj], 0, 0, 0);
            #pragma unroll
            for (int ti = 0; ti < 2; ++ti)
                #pragma unroll
                for (int tj = 0; tj < 4; ++tj)
                    acc[ti][tj] = __builtin_amdgcn_mfma_f32_32x32x16_bf16(
                        al[ti], bh[tj], acc[ti][tj], 0, 0, 0);
            __builtin_amdgcn_s_setprio(0);
        }
        asm volatile("s_barrier" ::: "memory");      // buffer n&1 free

        if ((n & 15) == 15) {
            // epilogue for col tile ct: dist' = ||e||^2 - 2*dot (xn drops out)
            const int ct = n >> 4;
            const int colbase = by * 1024 + ct * 256 + wcol;
            #pragma unroll
            for (int tj = 0; tj < 4; ++tj) {
                const int ci = colbase + tj * 32 + l31;
                const float en = enorm[ci];
                #pragma unroll
                for (int ti = 0; ti < 2; ++ti)
                    #pragma unroll
                    for (int r = 0; r < 16; ++r) {
                        float d = en - 2.0f * acc[ti][tj][r];
                        int s = ti * 16 + r;
                        if (d < bestd[s]) {
                            bestd[s] = d;
                            int sh = (s & 1) << 4;
                            bi2[s >> 1] = (bi2[s >> 1] & (0xFFFF0000u >> sh))
                                        | ((uint32)ci << sh);
                        }
                    }
            }
            #pragma unroll
            for (int i = 0; i < 2; ++i)
                #pragma unroll
                for (int j = 0; j < 4; ++j)
                    #pragma unroll
                    for (int r = 0; r < 16; ++r) acc[i][j][r] = 0.0f;
        }
    }

    // ---- per-wave shuffle argmin over the 32 col-classes (l31 lanes) ----
    // each row of the block is owned by exactly one wave; half (lane>>5)
    // selects the +4-row subgroup, so reduce within 32-lane halves.
    #pragma unroll
    for (int s = 0; s < 32; ++s) {
        float d = bestd[s];
        int   i = (int)((bi2[s >> 1] >> ((s & 1) << 4)) & 0xFFFFu);
        #pragma unroll
        for (int m = 16; m > 0; m >>= 1) {
            float d2 = __shfl_xor(d, m);
            int   i2 = __shfl_xor(i, m);
            if (d2 < d || (d2 == d && i2 < i)) { d = d2; i = i2; }
        }
        if (l31 == 0) {
            int ti = s >> 4, reg = s & 15;
            int row = wrow + ti * 32 + (reg & 3) + 8 * (reg >> 2) + 4 * half;
            size_t gr = (size_t)(bx * 256 + row);
            pmin[gr * 8 + by] = d;
            pidx[gr * 8 + by] = i;
        }
    }
}

// ===========================================================================
// Kernel 3: combine slice partials -> idx, then gather codebook row,
// exact fp32 ||x-e||^2 -> min_distances + loss partials. One 64-lane group/row.
__global__ __launch_bounds__(256) void finish_kernel(const float* __restrict__ x,
                                                     const float* __restrict__ cb,
                                                     const float* __restrict__ pmin,
                                                     const int* __restrict__ pidx,
                                                     float* __restrict__ out_idx,
                                                     float* __restrict__ qout,
                                                     float* __restrict__ out_mind,
                                                     float* __restrict__ lpart) {
    __shared__ float sred[4];
    int row  = blockIdx.x * 4 + (threadIdx.x >> 6);
    int lane = threadIdx.x & 63;

    // per-row argmin over the 8 slice partials (lanes 0..7 active)
    float d = (lane < 8) ? pmin[(size_t)row * 8 + lane] : 3.4e38f;
    int  ii = (lane < 8) ? pidx[(size_t)row * 8 + lane] : 0x7FFFFFFF;
    #pragma unroll
    for (int o = 4; o > 0; o >>= 1) {
        float d2 = __shfl_down(d, o);
        int   i2 = __shfl_down(ii, o);
        if (d2 < d || (d2 == d && i2 < ii)) { d = d2; ii = i2; }
    }
    int idx = __shfl(ii, 0);
    if (lane == 0) out_idx[row] = (float)idx;

    const float4* e4 = (const float4*)(cb + (size_t)idx * DIM);
    const float4* x4 = (const float4*)(x + (size_t)row * DIM);
    float4* q4 = (float4*)(qout + (size_t)row * DIM);
    float s = 0.0f;
    #pragma unroll
    for (int u = 0; u < 2; ++u) {
        float4 e  = e4[lane + u * 64];
        float4 xv = x4[lane + u * 64];
        q4[lane + u * 64] = e;
        float dx = xv.x - e.x, dy = xv.y - e.y, dz = xv.z - e.z, dw = xv.w - e.w;
        s += dx * dx + dy * dy + dz * dz + dw * dw;
    }
    #pragma unroll
    for (int o = 32; o > 0; o >>= 1) s += __shfl_down(s, o);
    if (lane == 0) { sred[threadIdx.x >> 6] = s; out_mind[row] = s; }
    __syncthreads();
    if (threadIdx.x == 0) lpart[blockIdx.x] = sred[0] + sred[1] + sred[2] + sred[3];
}

// ===========================================================================
// Kernel 4: final loss. loss_vq == loss_commit numerically => loss = 1.25*commit
__global__ __launch_bounds__(256) void loss_kernel(const float* __restrict__ lpart,
                                                   float* __restrict__ out_loss,
                                                   float* __restrict__ out_commit) {
    __shared__ float sm[256];
    float s = 0.0f;
    for (int i = threadIdx.x; i < 2048; i += 256) s += lpart[i];
    sm[threadIdx.x] = s;
    __syncthreads();
    #pragma unroll
    for (int o = 128; o > 0; o >>= 1) {
        if (threadIdx.x < o) sm[threadIdx.x] += sm[threadIdx.x + o];
        __syncthreads();
    }
    if (threadIdx.x == 0) {
        *out_commit = sm[0];
        *out_loss   = 1.25f * sm[0];
    }
}

// ===========================================================================
extern "C" void kernel_launch(void* const* d_in, const int* in_sizes, int n_in,
                              void* d_out, int out_size, void* d_ws, size_t ws_size,
                              hipStream_t stream) {
    const float* x  = (const float*)d_in[0];
    const float* cb = (const float*)d_in[1];
    float* out = (float*)d_out;
    float* ws  = (float*)d_ws;

    // A hi/lo staged in the quantized-output region (rewritten by finish_kernel)
    ushort_t* ahi = (ushort_t*)d_out;
    ushort_t* alo = (ushort_t*)d_out + 4194304;
    ushort_t* bhi = (ushort_t*)(ws + WS_BHI);
    ushort_t* blo = (ushort_t*)(ws + WS_BLO);
    float* enorm = ws + WS_ENORM;
    float* pmin  = ws + WS_PMIN;
    int*   pidx  = (int*)(ws + WS_PIDX);
    float* lpart = ws + WS_LPART;

    conv_kernel<<<4096, 256, 0, stream>>>(x, cb, ahi, alo, bhi, blo, enorm);
    vq_mfma_kernel<<<256, 512, 0, stream>>>(ahi, alo, bhi, blo, enorm, pmin, pidx);
    finish_kernel<<<NROWS / 4, 256, 0, stream>>>(x, cb, pmin, pidx,
                                                 out + OUT_IDX, out + OUT_Q,
                                                 out + OUT_MIND, lpart);
    loss_kernel<<<1, 256, 0, stream>>>(lpart, out + OUT_LOSS, out + OUT_COMMIT);
}

// Round 3
// 274.788 us; speedup vs baseline: 1.0325x; 1.0325x over previous
//
#include <hip/hip_runtime.h>

typedef __attribute__((ext_vector_type(8)))  short short8;   // 8 bf16 (4 VGPRs)
typedef __attribute__((ext_vector_type(16))) float f32x16;   // 32x32 MFMA acc
typedef unsigned short ushort_t;
typedef unsigned int uint32;

#define NROWS 8192
#define NCODE 8192
#define DIM   512

// ---------------- d_out layout (floats) ----------------
#define OUT_Q      0
#define OUT_LOSS   4194304
#define OUT_IDX    4194305
#define OUT_MIND   4202497
#define OUT_COMMIT 4210689

// ---------------- ws layout (floats) ----------------
#define WS_ENORM  0           // 8192
#define WS_PMIN   8192        // 8192*8
#define WS_PIDX   73728       // 8192*8 ints
#define WS_LPART  147456      // 2048
#define WS_BHI    150528      // 8192*512 bf16
#define WS_BLO    2247680

// ===========================================================================
__device__ inline uint32 bf16_rne(float f) {
    uint32 u = __float_as_uint(f);
    return (u + 0x7FFFu + ((u >> 16) & 1u)) >> 16;
}

__device__ inline void gload16(const ushort_t* g, ushort_t* l) {
    __builtin_amdgcn_global_load_lds(
        (const __attribute__((address_space(1))) void*)g,
        (__attribute__((address_space(3))) void*)l, 16, 0, 0);
}

// ===========================================================================
// Kernel 1: fused conversion of x and codebook into fragment-ordered bf16
// hi/lo tiles. Tile = 128 rows x 32 k, 8 KB, stored as 8 chunks of 1 KB:
//   chunk c = (r32)*2 + k16 ; within chunk lane L holds 8 bf16:
//   row = r32*32 + (L&31), k = k16*16 + (L>>5)*8 + j
// This IS the mfma_32x32x16 A/B fragment order -> conflict-free ds_read_b128
// and identity global_load_lds staging.
__global__ __launch_bounds__(256) void conv_kernel(const float* __restrict__ x,
                                                   const float* __restrict__ cb,
                                                   ushort_t* __restrict__ ahi,
                                                   ushort_t* __restrict__ alo,
                                                   ushort_t* __restrict__ bhi,
                                                   ushort_t* __restrict__ blo,
                                                   float* __restrict__ enorm) {
    int gid  = blockIdx.x * 256 + threadIdx.x;   // 0..1048575
    bool isA = gid < 524288;
    int g    = isA ? gid : gid - 524288;
    int row  = g >> 6;
    int lane = g & 63;
    int k0   = lane * 8;
    const float* src = (isA ? x : cb) + (size_t)row * DIM + k0;
    float v[8];
    *(float4*)&v[0] = *(const float4*)src;
    *(float4*)&v[4] = *(const float4*)(src + 4);
    float s = 0.0f;
    uint32 h[8], l[8];
    #pragma unroll
    for (int i = 0; i < 8; ++i) {
        s += v[i] * v[i];
        h[i] = bf16_rne(v[i]);
        float hf = __uint_as_float(h[i] << 16);
        l[i] = bf16_rne(v[i] - hf);
    }
    // fragment-ordered offset
    int tile = (row >> 7) * 16 + (k0 >> 5);
    int rp = row & 127, kp = k0 & 31;
    int c  = (rp >> 5) * 2 + (kp >> 4);
    int L  = (rp & 31) + (((kp >> 3) & 1) << 5);
    size_t off = (size_t)tile * 4096 + c * 512 + L * 8;   // ushort units
    uint4 ph, pl;
    ph.x = h[0] | (h[1] << 16); ph.y = h[2] | (h[3] << 16);
    ph.z = h[4] | (h[5] << 16); ph.w = h[6] | (h[7] << 16);
    pl.x = l[0] | (l[1] << 16); pl.y = l[2] | (l[3] << 16);
    pl.z = l[4] | (l[5] << 16); pl.w = l[6] | (l[7] << 16);
    if (isA) {
        *(uint4*)(ahi + off) = ph;
        *(uint4*)(alo + off) = pl;
    } else {
        *(uint4*)(bhi + off) = ph;
        *(uint4*)(blo + off) = pl;
        #pragma unroll
        for (int o = 32; o > 0; o >>= 1) s += __shfl_down(s, o);
        if (lane == 0) enorm[row] = s;
    }
}

// ===========================================================================
// Kernel 2: MFMA distance-GEMM + fused per-row argmin.
// R3: cross-iteration register pipelining. At iter n, MFMA clusters consume
// fragments ds_read at iter n-1; reads for n+1 are issued BETWEEN clusters.
// No MFMA ever waits on a same-phase ds_read -> LDS pipe hides under matrix.
// Geometry: 256 thr / 4 waves (2 wr x 2 wc), wave tile 64x128 (acc[2][4]),
// block tile 128 rows x 256 cols, K-step 16, triple-buffered LDS
// (3 x 24 KB = 72 KB -> 2 blocks/CU). One raw s_barrier + vmcnt(6) per iter.
// Argmin index packed into distance mantissa (19-bit d | 13-bit col) ->
// no index registers, no ties. Cross-wc merge via 1 KB LDS at the end.
struct Frags { short8 ah[2]; short8 al[2]; short8 bh[4]; short8 bl[4]; };

__global__ __launch_bounds__(256, 2) void vq_mfma_kernel(
        const ushort_t* __restrict__ ahi, const ushort_t* __restrict__ alo,
        const ushort_t* __restrict__ bhi, const ushort_t* __restrict__ blo,
        const float* __restrict__ enorm,
        float* __restrict__ pmin, int* __restrict__ pidx) {
    // 3 buffers x 12288 ushorts: Ah[0,2K) Al[2K,4K) Bh[4K,8K) Bl[8K,12K)
    __shared__ __align__(16) ushort_t smem[36864];   // 72 KB

    const int tid  = threadIdx.x;            // 0..255
    const int wave = tid >> 6, lane = tid & 63;
    const int l31  = lane & 31, half = lane >> 5;
    const int q  = blockIdx.x;
    const int bx = (q & 7) * 8 + (q >> 6);   // 0..63 (128-row block), XCD=q&7
    const int by = (q >> 3) & 7;             // 0..7  (1024-col slice)
    const int wr = wave >> 1;                // 0..1 row group (64 rows)
    const int wc = wave & 1;                 // 0..1 col group (128 cols)
    const int wr2 = wr * 2, wc4 = wc * 4;
    const int l8 = lane * 8;

    f32x16 acc[2][4];
    #pragma unroll
    for (int i = 0; i < 2; ++i)
        #pragma unroll
        for (int j = 0; j < 4; ++j)
            #pragma unroll
            for (int r = 0; r < 16; ++r) acc[i][j][r] = 0.0f;

    float keys[32];                          // packed: trunc(d) | col-index
    #pragma unroll
    for (int i = 0; i < 32; ++i) keys[i] = 3.4e38f;

    // ---- stage K16-step nn into buffer nn%3 (6 gloads, 24 KB) ----
    auto stage = [&](int nn) {
        const int kb = nn & 31, kc = kb >> 1, k16 = kb & 1;
        const int ct = nn >> 5;
        ushort_t* S2 = smem + (nn % 3) * 12288;
        const int lo = (tid >> 6) * 1024 + (k16 << 9) + (tid & 63) * 8;
        const size_t at = ((size_t)bx * 16 + kc) << 12;
        gload16(ahi + at + lo, S2 + tid * 8);
        gload16(alo + at + lo, S2 + 2048 + tid * 8);
        const int c0 = by * 8 + ct * 2;
        const size_t bt0 = ((size_t)c0 * 16 + kc) << 12;
        const size_t bt1 = bt0 + ((size_t)16 << 12);
        gload16(bhi + bt0 + lo, S2 + 4096 + tid * 8);
        gload16(bhi + bt1 + lo, S2 + 6144 + tid * 8);
        gload16(blo + bt0 + lo, S2 + 8192 + tid * 8);
        gload16(blo + bt1 + lo, S2 + 10240 + tid * 8);
    };

#define RD(base) (*(const short8*)&Sr[(base) + l8])
#define MFMA8(A, B) do {                                                      \
    __builtin_amdgcn_s_setprio(1);                                            \
    _Pragma("unroll")                                                         \
    for (int ti = 0; ti < 2; ++ti)                                            \
        _Pragma("unroll")                                                     \
        for (int tj = 0; tj < 4; ++tj)                                        \
            acc[ti][tj] = __builtin_amdgcn_mfma_f32_32x32x16_bf16(            \
                (A)[ti], (B)[tj], acc[ti][tj], 0, 0, 0);                      \
    __builtin_amdgcn_s_setprio(0);                                            \
} while (0)

#define BODY(nn, CUR, NXT) do {                                               \
    if ((nn) + 2 < 128) {                                                     \
        stage((nn) + 2);                                                      \
        asm volatile("s_waitcnt vmcnt(6)" ::: "memory");                      \
    } else {                                                                  \
        asm volatile("s_waitcnt vmcnt(0)" ::: "memory");                      \
    }                                                                         \
    asm volatile("s_barrier" ::: "memory");                                   \
    __builtin_amdgcn_sched_barrier(0);                                        \
    const ushort_t* Sr = smem + (((nn) + 1) % 3) * 12288;                     \
    MFMA8(CUR.ah, CUR.bh);                          /* C0 */                  \
    NXT.ah[0] = RD((wr2 + 0) * 512);                /* R1: A-hi, B-hi */      \
    NXT.ah[1] = RD((wr2 + 1) * 512);                                          \
    NXT.bh[0] = RD(4096 + (wc4 + 0) * 512);                                   \
    NXT.bh[1] = RD(4096 + (wc4 + 1) * 512);                                   \
    NXT.bh[2] = RD(4096 + (wc4 + 2) * 512);                                   \
    NXT.bh[3] = RD(4096 + (wc4 + 3) * 512);                                   \
    MFMA8(CUR.ah, CUR.bl);                          /* C1 */                  \
    NXT.bl[0] = RD(8192 + (wc4 + 0) * 512);         /* R2: B-lo, A-lo */      \
    NXT.bl[1] = RD(8192 + (wc4 + 1) * 512);                                   \
    NXT.bl[2] = RD(8192 + (wc4 + 2) * 512);                                   \
    NXT.bl[3] = RD(8192 + (wc4 + 3) * 512);                                   \
    NXT.al[0] = RD(2048 + (wr2 + 0) * 512);                                   \
    NXT.al[1] = RD(2048 + (wr2 + 1) * 512);                                   \
    MFMA8(CUR.al, CUR.bh);                          /* C2 */                  \
    if (((nn) & 31) == 31) {                                                  \
        const int ct = (nn) >> 5;                                             \
        const int colbase = by * 1024 + ct * 256 + wc * 128;                  \
        _Pragma("unroll")                                                     \
        for (int tj = 0; tj < 4; ++tj) {                                      \
            const int ci = colbase + tj * 32 + l31;                           \
            const float en = enorm[ci];                                       \
            _Pragma("unroll")                                                 \
            for (int ti = 0; ti < 2; ++ti)                                    \
                _Pragma("unroll")                                             \
                for (int r = 0; r < 16; ++r) {                                \
                    float d = en - 2.0f * acc[ti][tj][r];                     \
                    float cand = __uint_as_float(                             \
                        (__float_as_uint(d) & 0xFFFFE000u) | (uint32)ci);     \
                    int s = ti * 16 + r;                                      \
                    if (cand < keys[s]) keys[s] = cand;                       \
                }                                                             \
        }                                                                     \
        _Pragma("unroll")                                                     \
        for (int i = 0; i < 2; ++i)                                           \
            _Pragma("unroll")                                                 \
            for (int j = 0; j < 4; ++j)                                       \
                _Pragma("unroll")                                             \
                for (int r = 0; r < 16; ++r) acc[i][j][r] = 0.0f;             \
    }                                                                         \
} while (0)

    Frags Fa, Fb;

    // ---- prologue: stage 0,1; read frag set for iter 0 ----
    stage(0); stage(1);
    asm volatile("s_waitcnt vmcnt(6)" ::: "memory");
    __syncthreads();
    {
        const ushort_t* Sr = smem;           // buffer 0
        Fa.ah[0] = RD((wr2 + 0) * 512);  Fa.ah[1] = RD((wr2 + 1) * 512);
        Fa.al[0] = RD(2048 + (wr2 + 0) * 512);
        Fa.al[1] = RD(2048 + (wr2 + 1) * 512);
        #pragma unroll
        for (int tj = 0; tj < 4; ++tj) {
            Fa.bh[tj] = RD(4096 + (wc4 + tj) * 512);
            Fa.bl[tj] = RD(8192 + (wc4 + tj) * 512);
        }
    }

    for (int n = 0; n < 128; n += 2) {
        BODY(n, Fa, Fb);
        BODY(n + 1, Fb, Fa);
    }

    // ---- cross-wc merge: 2 candidates per row via 1 KB LDS ----
    __syncthreads();                          // drains loop; frees smem
    float* rd = (float*)smem;                 // [wc][128 rows]
    #pragma unroll
    for (int s = 0; s < 32; ++s) {
        float k = keys[s];
        #pragma unroll
        for (int m = 16; m > 0; m >>= 1) k = fminf(k, __shfl_xor(k, m));
        if (l31 == 0) {
            int r = s & 15;
            int row = wr * 64 + (s >> 4) * 32 + (r & 3) + 8 * (r >> 2) + 4 * half;
            rd[wc * 128 + row] = k;
        }
    }
    __syncthreads();
    if (tid < 128) {
        float k = fminf(rd[tid], rd[128 + tid]);
        size_t gr = (size_t)bx * 128 + tid;
        pmin[gr * 8 + by] = k;
        pidx[gr * 8 + by] = (int)(__float_as_uint(k) & 8191u);
    }
#undef RD
#undef MFMA8
#undef BODY
}

// ===========================================================================
// Kernel 3: combine slice partials -> idx, then gather codebook row,
// exact fp32 ||x-e||^2 -> min_distances + loss partials. One 64-lane group/row.
__global__ __launch_bounds__(256) void finish_kernel(const float* __restrict__ x,
                                                     const float* __restrict__ cb,
                                                     const float* __restrict__ pmin,
                                                     const int* __restrict__ pidx,
                                                     float* __restrict__ out_idx,
                                                     float* __restrict__ qout,
                                                     float* __restrict__ out_mind,
                                                     float* __restrict__ lpart) {
    __shared__ float sred[4];
    int row  = blockIdx.x * 4 + (threadIdx.x >> 6);
    int lane = threadIdx.x & 63;

    // per-row argmin over the 8 slice partials (lanes 0..7 active)
    float d = (lane < 8) ? pmin[(size_t)row * 8 + lane] : 3.4e38f;
    int  ii = (lane < 8) ? pidx[(size_t)row * 8 + lane] : 0x7FFFFFFF;
    #pragma unroll
    for (int o = 4; o > 0; o >>= 1) {
        float d2 = __shfl_down(d, o);
        int   i2 = __shfl_down(ii, o);
        if (d2 < d || (d2 == d && i2 < ii)) { d = d2; ii = i2; }
    }
    int idx = __shfl(ii, 0);
    if (lane == 0) out_idx[row] = (float)idx;

    const float4* e4 = (const float4*)(cb + (size_t)idx * DIM);
    const float4* x4 = (const float4*)(x + (size_t)row * DIM);
    float4* q4 = (float4*)(qout + (size_t)row * DIM);
    float s = 0.0f;
    #pragma unroll
    for (int u = 0; u < 2; ++u) {
        float4 e  = e4[lane + u * 64];
        float4 xv = x4[lane + u * 64];
        q4[lane + u * 64] = e;
        float dx = xv.x - e.x, dy = xv.y - e.y, dz = xv.z - e.z, dw = xv.w - e.w;
        s += dx * dx + dy * dy + dz * dz + dw * dw;
    }
    #pragma unroll
    for (int o = 32; o > 0; o >>= 1) s += __shfl_down(s, o);
    if (lane == 0) { sred[threadIdx.x >> 6] = s; out_mind[row] = s; }
    __syncthreads();
    if (threadIdx.x == 0) lpart[blockIdx.x] = sred[0] + sred[1] + sred[2] + sred[3];
}

// ===========================================================================
// Kernel 4: final loss. loss_vq == loss_commit numerically => loss = 1.25*commit
__global__ __launch_bounds__(256) void loss_kernel(const float* __restrict__ lpart,
                                                   float* __restrict__ out_loss,
                                                   float* __restrict__ out_commit) {
    __shared__ float sm[256];
    float s = 0.0f;
    for (int i = threadIdx.x; i < 2048; i += 256) s += lpart[i];
    sm[threadIdx.x] = s;
    __syncthreads();
    #pragma unroll
    for (int o = 128; o > 0; o >>= 1) {
        if (threadIdx.x < o) sm[threadIdx.x] += sm[threadIdx.x + o];
        __syncthreads();
    }
    if (threadIdx.x == 0) {
        *out_commit = sm[0];
        *out_loss   = 1.25f * sm[0];
    }
}

// ===========================================================================
extern "C" void kernel_launch(void* const* d_in, const int* in_sizes, int n_in,
                              void* d_out, int out_size, void* d_ws, size_t ws_size,
                              hipStream_t stream) {
    const float* x  = (const float*)d_in[0];
    const float* cb = (const float*)d_in[1];
    float* out = (float*)d_out;
    float* ws  = (float*)d_ws;

    // A hi/lo staged in the quantized-output region (rewritten by finish_kernel)
    ushort_t* ahi = (ushort_t*)d_out;
    ushort_t* alo = (ushort_t*)d_out + 4194304;
    ushort_t* bhi = (ushort_t*)(ws + WS_BHI);
    ushort_t* blo = (ushort_t*)(ws + WS_BLO);
    float* enorm = ws + WS_ENORM;
    float* pmin  = ws + WS_PMIN;
    int*   pidx  = (int*)(ws + WS_PIDX);
    float* lpart = ws + WS_LPART;

    conv_kernel<<<4096, 256, 0, stream>>>(x, cb, ahi, alo, bhi, blo, enorm);
    vq_mfma_kernel<<<512, 256, 0, stream>>>(ahi, alo, bhi, blo, enorm, pmin, pidx);
    finish_kernel<<<NROWS / 4, 256, 0, stream>>>(x, cb, pmin, pidx,
                                                 out + OUT_IDX, out + OUT_Q,
                                                 out + OUT_MIND, lpart);
    loss_kernel<<<1, 256, 0, stream>>>(lpart, out + OUT_LOSS, out + OUT_COMMIT);
}